// Round 1
// baseline (5486.453 us; speedup 1.0000x reference)
//
#include <hip/hip_runtime.h>
#include <math.h>

#define BB 8
#define NN 2048
#define PP 64
#define KK 32
#define DD 384
#define DEPTH 12
#define DI 768
#define DS 16
#define DCONV 4
#define DTR 24
#define NC 40
#define LL 128  // 2*PP

// ---------------------------------------------------------------- helpers
__device__ __forceinline__ float gelu_exact(float x) {
    return 0.5f * x * (1.0f + erff(x * 0.70710678118654752440f));
}
__device__ __forceinline__ float siluf(float x) {
    return x / (1.0f + expf(-x));
}
__device__ __forceinline__ unsigned spread_bits(unsigned v) {
    v &= 1023u;
    v = (v | (v << 16)) & 50331903u;
    v = (v | (v << 8)) & 50393103u;
    v = (v | (v << 4)) & 51130563u;
    v = (v | (v << 2)) & 153391689u;
    return v;
}

// ---------------------------------------------------------------- patch embed
// one workgroup per (b, p): KNN select (stable argmin x32), then
// 3->64->128->384 MLP over 32 neighbors, max-pool over neighbors.
__global__ __launch_bounds__(256) void k_patch_embed(
    const float* __restrict__ data,
    const float* __restrict__ w1, const float* __restrict__ b1,
    const float* __restrict__ g1, const float* __restrict__ be1,
    const float* __restrict__ w2, const float* __restrict__ b2,
    const float* __restrict__ g2, const float* __restrict__ be2,
    const float* __restrict__ w3, const float* __restrict__ b3,
    const float* __restrict__ g3, const float* __restrict__ be3,
    float* __restrict__ tokens, float* __restrict__ centers)
{
    const int bp = blockIdx.x;
    const int b = bp >> 6, p = bp & 63;
    const int tid = threadIdx.x;
    const float* X = data + (size_t)b * NN * 3;
    const float inv_den = 0.99999500003749968752f; // 1/sqrt(1+1e-5)

    const float cx = X[p * 32 * 3 + 0];
    const float cy = X[p * 32 * 3 + 1];
    const float cz = X[p * 32 * 3 + 2];
    if (tid == 0) {
        centers[(b * PP + p) * 3 + 0] = cx;
        centers[(b * PP + p) * 3 + 1] = cy;
        centers[(b * PP + p) * 3 + 2] = cz;
    }

    __shared__ float d2[NN];
    for (int i = tid; i < NN; i += 256) {
        float dx = cx - X[i * 3 + 0];
        float dy = cy - X[i * 3 + 1];
        float dz = cz - X[i * 3 + 2];
        d2[i] = dx * dx + dy * dy + dz * dz;
    }
    __syncthreads();

    __shared__ int knn[KK];
    __shared__ float rv[256];
    __shared__ int ri[256];
    for (int k = 0; k < KK; k++) {
        float bv = 3.4e38f; int bi = NN;
        for (int i = tid; i < NN; i += 256) {
            float v = d2[i];
            if (v < bv) { bv = v; bi = i; }   // strict <: earliest index wins per-thread
        }
        rv[tid] = bv; ri[tid] = bi;
        __syncthreads();
        for (int s = 128; s > 0; s >>= 1) {
            if (tid < s) {
                float ov = rv[tid + s]; int oi = ri[tid + s];
                if (ov < rv[tid] || (ov == rv[tid] && oi < ri[tid])) { rv[tid] = ov; ri[tid] = oi; }
            }
            __syncthreads();
        }
        if (tid == 0) { knn[k] = ri[0]; d2[ri[0]] = 3.4e38f; }
        __syncthreads();
    }

    __shared__ float nx[KK * 3];
    for (int j = tid; j < KK; j += 256) {
        int q = knn[j];
        nx[j * 3 + 0] = X[q * 3 + 0] - cx;
        nx[j * 3 + 1] = X[q * 3 + 1] - cy;
        nx[j * 3 + 2] = X[q * 3 + 2] - cz;
    }
    __syncthreads();

    __shared__ float h1[KK * 64];
    for (int e = tid; e < KK * 64; e += 256) {
        int j = e >> 6, c = e & 63;
        float v = nx[j * 3 + 0] * w1[c * 3 + 0] + nx[j * 3 + 1] * w1[c * 3 + 1] +
                  nx[j * 3 + 2] * w1[c * 3 + 2] + b1[c];
        v = v * (g1[c] * inv_den) + be1[c];
        h1[j * 64 + c] = gelu_exact(v);
    }
    __syncthreads();

    __shared__ float h2[KK * 128];
    for (int e = tid; e < KK * 128; e += 256) {
        int j = e >> 7, c = e & 127;
        float acc = 0.f;
        const float* wr = w2 + c * 64;
        const float* hr = h1 + j * 64;
        for (int k = 0; k < 64; k++) acc += hr[k] * wr[k];
        float v = (acc + b2[c]) * (g2[c] * inv_den) + be2[c];
        h2[j * 128 + c] = gelu_exact(v);
    }
    __syncthreads();

    for (int c = tid; c < DD; c += 256) {
        const float* wr = w3 + (size_t)c * 128;
        float sc = g3[c] * inv_den;
        float bi2 = b3[c], sh = be3[c];
        float m = -3.4e38f;
        for (int j = 0; j < KK; j++) {
            const float* hr = h2 + j * 128;
            float acc = 0.f;
            for (int k = 0; k < 128; k++) acc += hr[k] * wr[k];
            float v = (acc + bi2) * sc + sh;
            m = fmaxf(m, v);
        }
        tokens[((size_t)b * PP + p) * DD + c] = m;
    }
}

// ---------------------------------------------------------------- SFC orders
__global__ __launch_bounds__(64) void k_sfc(const float* __restrict__ centers,
                                            int* __restrict__ order_h,
                                            int* __restrict__ order_th)
{
    const int b = blockIdx.x;
    const int tid = threadIdx.x; // 0..63
    float cc[3];
    cc[0] = centers[(b * PP + tid) * 3 + 0];
    cc[1] = centers[(b * PP + tid) * 3 + 1];
    cc[2] = centers[(b * PP + tid) * 3 + 2];

    __shared__ float csh[PP][3];
    __shared__ float slo[3], shi[3];
    csh[tid][0] = cc[0]; csh[tid][1] = cc[1]; csh[tid][2] = cc[2];
    __syncthreads();
    if (tid == 0) {
        for (int k = 0; k < 3; k++) {
            float lo = csh[0][k], hi = csh[0][k];
            for (int j = 1; j < PP; j++) { lo = fminf(lo, csh[j][k]); hi = fmaxf(hi, csh[j][k]); }
            slo[k] = lo; shi[k] = hi;
        }
    }
    __syncthreads();

    int q[3];
    for (int k = 0; k < 3; k++) {
        float t = (cc[k] - slo[k]) / (shi[k] - slo[k] + 1e-6f) * 1023.0f;
        int qi = (int)t;                 // trunc toward zero, same as astype(int32)
        qi = qi < 0 ? 0 : (qi > 1023 ? 1023 : qi);
        q[k] = qi;
    }
    unsigned kh = spread_bits((unsigned)q[0]) | (spread_bits((unsigned)q[1]) << 1) |
                  (spread_bits((unsigned)q[2]) << 2);
    unsigned kt = spread_bits((unsigned)q[2]) | (spread_bits((unsigned)q[1]) << 1) |
                  (spread_bits((unsigned)q[0]) << 2);

    __shared__ unsigned khs[PP], kts[PP];
    khs[tid] = kh; kts[tid] = kt;
    __syncthreads();
    int rh = 0, rt = 0;
    for (int j = 0; j < PP; j++) {
        unsigned a = khs[j];
        rh += (a < kh) || (a == kh && j < tid);
        unsigned c = kts[j];
        rt += (c < kt) || (c == kt && j < tid);
    }
    order_h[b * PP + rh] = tid;
    order_th[b * PP + rt] = tid;
}

// ---------------------------------------------------------------- build token sequence
__global__ void k_build_t(const float* __restrict__ tokens,
                          const int* __restrict__ order_h, const int* __restrict__ order_th,
                          const float* __restrict__ hs, const float* __restrict__ hb,
                          const float* __restrict__ ts, const float* __restrict__ tb,
                          const float* __restrict__ pos, float* __restrict__ t)
{
    int idx = blockIdx.x * blockDim.x + threadIdx.x;
    if (idx >= BB * LL * DD) return;
    int d = idx % DD;
    int l = (idx / DD) % LL;
    int b = idx / (DD * LL);
    float v;
    if (l < PP) {
        int src = order_h[b * PP + l];
        v = tokens[((size_t)b * PP + src) * DD + d] * hs[d] + hb[d] + pos[l * DD + d];
    } else {
        int ll2 = l - PP;
        int src = order_th[b * PP + ll2];
        v = tokens[((size_t)b * PP + src) * DD + d] * ts[d] + tb[d] + pos[ll2 * DD + d];
    }
    t[idx] = v;
}

// ---------------------------------------------------------------- layernorm (one block per token)
__global__ __launch_bounds__(128) void k_ln(const float* __restrict__ x,
                                            const float* __restrict__ g,
                                            const float* __restrict__ bb,
                                            float* __restrict__ y)
{
    const int row = blockIdx.x;
    const int tid = threadIdx.x;
    const float* xr = x + (size_t)row * DD;
    __shared__ float red[128];
    float s = 0.f;
    for (int i = tid; i < DD; i += 128) s += xr[i];
    red[tid] = s; __syncthreads();
    for (int st = 64; st > 0; st >>= 1) { if (tid < st) red[tid] += red[tid + st]; __syncthreads(); }
    float mean = red[0] / (float)DD;
    __syncthreads();
    float v = 0.f;
    for (int i = tid; i < DD; i += 128) { float dd = xr[i] - mean; v += dd * dd; }
    red[tid] = v; __syncthreads();
    for (int st = 64; st > 0; st >>= 1) { if (tid < st) red[tid] += red[tid + st]; __syncthreads(); }
    float var = red[0] / (float)DD;
    float inv = 1.0f / sqrtf(var + 1e-5f);
    for (int i = tid; i < DD; i += 128)
        y[(size_t)row * DD + i] = (xr[i] - mean) * inv * g[i] + bb[i];
}

// ---------------------------------------------------------------- tiled fp32 GEMM  C[n,m] = sum_k A[n,k]*B[m,k]
// ACT: 0 none, 1 softplus.  BETA: 0 overwrite, 1 accumulate into C.
template <int ACT, int BETA>
__global__ __launch_bounds__(256) void k_gemm_nt(
    const float* __restrict__ A, int lda,
    const float* __restrict__ Bm, int ldb,
    const float* __restrict__ bias,
    float* __restrict__ C, int ldc,
    int nrows, int mcols, int kdim)
{
    __shared__ float As[16][17], Bs[16][17];
    const int tx = threadIdx.x, ty = threadIdx.y;
    const int row = blockIdx.y * 16 + ty;
    const int col = blockIdx.x * 16 + tx;
    float acc = 0.f;
    for (int k0 = 0; k0 < kdim; k0 += 16) {
        int ka = k0 + tx;
        As[ty][tx] = (row < nrows && ka < kdim) ? A[(size_t)row * lda + ka] : 0.f;
        int bm = blockIdx.x * 16 + ty;
        Bs[ty][tx] = (bm < mcols && ka < kdim) ? Bm[(size_t)bm * ldb + ka] : 0.f;
        __syncthreads();
#pragma unroll
        for (int kk = 0; kk < 16; kk++) acc += As[ty][kk] * Bs[tx][kk];
        __syncthreads();
    }
    if (row < nrows && col < mcols) {
        float v = acc;
        if (bias) v += bias[col];
        if (ACT == 1) v = fmaxf(v, 0.f) + log1pf(expf(-fabsf(v)));  // softplus
        float* cp = C + (size_t)row * ldc + col;
        if (BETA) *cp += v; else *cp = v;
    }
}

// ---------------------------------------------------------------- causal depthwise conv + silu
__global__ void k_conv(const float* __restrict__ xz, const float* __restrict__ cw,
                       const float* __restrict__ cb, float* __restrict__ xc)
{
    int idx = blockIdx.x * blockDim.x + threadIdx.x;
    if (idx >= BB * LL * DI) return;
    int c = idx % DI;
    int l = (idx / DI) % LL;
    int b = idx / (DI * LL);
    float acc = cb[c];
#pragma unroll
    for (int j = 0; j < DCONV; j++) {
        int lt = l - (DCONV - 1) + j;
        if (lt >= 0) acc += xz[((size_t)(b * LL + lt)) * (2 * DI) + c] * cw[c * DCONV + j];
    }
    xc[idx] = siluf(acc);
}

// ---------------------------------------------------------------- selective scan, fused D-skip + gate
__global__ __launch_bounds__(256) void k_scan(
    const float* __restrict__ delta, const float* __restrict__ xdbl,
    const float* __restrict__ xc, const float* __restrict__ xz,
    const float* __restrict__ Alog, const float* __restrict__ Dp,
    float* __restrict__ y)
{
    int idx = blockIdx.x * blockDim.x + threadIdx.x;
    if (idx >= BB * DI) return;
    int b = idx / DI, d = idx % DI;
    float A[DS], h[DS];
#pragma unroll
    for (int s = 0; s < DS; s++) { A[s] = -expf(Alog[d * DS + s]); h[s] = 0.f; }
    float Dd = Dp[d];
    for (int t = 0; t < LL; t++) {
        size_t row = (size_t)b * LL + t;
        float dt = delta[row * DI + d];
        float u  = xc[row * DI + d];
        float du = dt * u;
        const float* xd = xdbl + row * (DTR + 2 * DS);
        float acc = 0.f;
#pragma unroll
        for (int s = 0; s < DS; s++) {
            float hb = h[s] * expf(dt * A[s]) + du * xd[DTR + s];
            h[s] = hb;
            acc += hb * xd[DTR + DS + s];
        }
        float z = xz[row * (2 * DI) + DI + d];
        y[row * DI + d] = (acc + Dd * u) * siluf(z);
    }
}

// ---------------------------------------------------------------- mean over L
__global__ void k_mean(const float* __restrict__ xln, float* __restrict__ pooled)
{
    int idx = blockIdx.x * blockDim.x + threadIdx.x;
    if (idx >= BB * DD) return;
    int b = idx / DD, d = idx % DD;
    float s = 0.f;
    for (int l = 0; l < LL; l++) s += xln[((size_t)b * LL + l) * DD + d];
    pooled[idx] = s / (float)LL;
}

// ---------------------------------------------------------------- head MLP (one block per batch)
__global__ __launch_bounds__(256) void k_mlp(const float* __restrict__ pooled,
    const float* __restrict__ w1, const float* __restrict__ b1,
    const float* __restrict__ w2, const float* __restrict__ b2,
    const float* __restrict__ w3, const float* __restrict__ b3,
    float* __restrict__ out)
{
    int b = blockIdx.x, tid = threadIdx.x;
    __shared__ float pl[DD];
    __shared__ float h1[256];
    __shared__ float h2[64];
    for (int i = tid; i < DD; i += 256) pl[i] = pooled[b * DD + i];
    __syncthreads();
    {
        float acc = b1[tid];
        const float* wr = w1 + (size_t)tid * DD;
        for (int k = 0; k < DD; k++) acc += pl[k] * wr[k];
        h1[tid] = fmaxf(acc, 0.f);
    }
    __syncthreads();
    if (tid < 64) {
        float acc = b2[tid];
        const float* wr = w2 + (size_t)tid * 256;
        for (int k = 0; k < 256; k++) acc += h1[k] * wr[k];
        h2[tid] = fmaxf(acc, 0.f);
    }
    __syncthreads();
    if (tid < NC) {
        float acc = b3[tid];
        const float* wr = w3 + (size_t)tid * 64;
        for (int k = 0; k < 64; k++) acc += h2[k] * wr[k];
        out[b * NC + tid] = acc;
    }
}

// ---------------------------------------------------------------- launch
extern "C" void kernel_launch(void* const* d_in, const int* in_sizes, int n_in,
                              void* d_out, int out_size, void* d_ws, size_t ws_size,
                              hipStream_t stream)
{
    const float* data      = (const float*)d_in[0];
    const float* pe_w1     = (const float*)d_in[1];
    const float* pe_b1     = (const float*)d_in[2];
    const float* pe_g1     = (const float*)d_in[3];
    const float* pe_be1    = (const float*)d_in[4];
    const float* pe_w2     = (const float*)d_in[5];
    const float* pe_b2     = (const float*)d_in[6];
    const float* pe_g2     = (const float*)d_in[7];
    const float* pe_be2    = (const float*)d_in[8];
    const float* pe_w3     = (const float*)d_in[9];
    const float* pe_b3     = (const float*)d_in[10];
    const float* pe_g3     = (const float*)d_in[11];
    const float* pe_be3    = (const float*)d_in[12];
    const float* oi_h_scale  = (const float*)d_in[13];
    const float* oi_h_shift  = (const float*)d_in[14];
    const float* oi_th_scale = (const float*)d_in[15];
    const float* oi_th_shift = (const float*)d_in[16];
    const float* pos_embed = (const float*)d_in[17];
    const float* blk_ln_g  = (const float*)d_in[18];
    const float* blk_ln_b  = (const float*)d_in[19];
    const float* blk_in_w  = (const float*)d_in[20];
    const float* blk_conv_w = (const float*)d_in[21];
    const float* blk_conv_b = (const float*)d_in[22];
    const float* blk_xp_w  = (const float*)d_in[23];
    const float* blk_dt_w  = (const float*)d_in[24];
    const float* blk_dt_b  = (const float*)d_in[25];
    const float* blk_Alog  = (const float*)d_in[26];
    const float* blk_D     = (const float*)d_in[27];
    const float* blk_out_w = (const float*)d_in[28];
    const float* norm_g    = (const float*)d_in[29];
    const float* norm_b    = (const float*)d_in[30];
    const float* mlp_w1    = (const float*)d_in[31];
    const float* mlp_b1    = (const float*)d_in[32];
    const float* mlp_w2    = (const float*)d_in[33];
    const float* mlp_b2    = (const float*)d_in[34];
    const float* mlp_w3    = (const float*)d_in[35];
    const float* mlp_b3    = (const float*)d_in[36];

    float* ws = (float*)d_ws;
    size_t off = 0;
    auto alloc = [&](size_t n) { float* p = ws + off; off += (n + 63) & ~(size_t)63; return p; };
    float* tokens  = alloc((size_t)BB * PP * DD);
    float* centers = alloc((size_t)BB * PP * 3);
    int*   order_h = (int*)alloc((size_t)BB * PP);
    int*   order_th= (int*)alloc((size_t)BB * PP);
    float* t    = alloc((size_t)BB * LL * DD);
    float* xln  = alloc((size_t)BB * LL * DD);
    float* xz   = alloc((size_t)BB * LL * 2 * DI);
    float* xc   = alloc((size_t)BB * LL * DI);
    float* xdbl = alloc((size_t)BB * LL * (DTR + 2 * DS));
    float* delta= alloc((size_t)BB * LL * DI);
    float* yb   = alloc((size_t)BB * LL * DI);
    float* pooled = alloc((size_t)BB * DD);

    k_patch_embed<<<BB * PP, 256, 0, stream>>>(data,
        pe_w1, pe_b1, pe_g1, pe_be1, pe_w2, pe_b2, pe_g2, pe_be2,
        pe_w3, pe_b3, pe_g3, pe_be3, tokens, centers);
    k_sfc<<<BB, 64, 0, stream>>>(centers, order_h, order_th);
    {
        int nt = BB * LL * DD;
        k_build_t<<<(nt + 255) / 256, 256, 0, stream>>>(tokens, order_h, order_th,
            oi_h_scale, oi_h_shift, oi_th_scale, oi_th_shift, pos_embed, t);
    }

    const int NR = BB * LL; // 1024
    dim3 gblk(16, 16);
    for (int i = 0; i < DEPTH; i++) {
        const float* ln_g = blk_ln_g + i * DD;
        const float* ln_b = blk_ln_b + i * DD;
        const float* in_w = blk_in_w + (size_t)i * 2 * DI * DD;
        const float* cw   = blk_conv_w + (size_t)i * DI * DCONV;
        const float* cb   = blk_conv_b + (size_t)i * DI;
        const float* xp   = blk_xp_w + (size_t)i * (DTR + 2 * DS) * DI;
        const float* dtw  = blk_dt_w + (size_t)i * DI * DTR;
        const float* dtb  = blk_dt_b + (size_t)i * DI;
        const float* Al   = blk_Alog + (size_t)i * DI * DS;
        const float* Dpp  = blk_D + (size_t)i * DI;
        const float* ow   = blk_out_w + (size_t)i * DD * DI;

        k_ln<<<NR, 128, 0, stream>>>(t, ln_g, ln_b, xln);
        k_gemm_nt<0, 0><<<dim3((2 * DI + 15) / 16, (NR + 15) / 16), gblk, 0, stream>>>(
            xln, DD, in_w, DD, nullptr, xz, 2 * DI, NR, 2 * DI, DD);
        k_conv<<<(NR * DI + 255) / 256, 256, 0, stream>>>(xz, cw, cb, xc);
        k_gemm_nt<0, 0><<<dim3((DTR + 2 * DS + 15) / 16, (NR + 15) / 16), gblk, 0, stream>>>(
            xc, DI, xp, DI, nullptr, xdbl, DTR + 2 * DS, NR, DTR + 2 * DS, DI);
        k_gemm_nt<1, 0><<<dim3((DI + 15) / 16, (NR + 15) / 16), gblk, 0, stream>>>(
            xdbl, DTR + 2 * DS, dtw, DTR, dtb, delta, DI, NR, DI, DTR);
        k_scan<<<(BB * DI + 255) / 256, 256, 0, stream>>>(delta, xdbl, xc, xz, Al, Dpp, yb);
        k_gemm_nt<0, 1><<<dim3((DD + 15) / 16, (NR + 15) / 16), gblk, 0, stream>>>(
            yb, DI, ow, DI, nullptr, t, DD, NR, DD, DI);
    }

    k_ln<<<NR, 128, 0, stream>>>(t, norm_g, norm_b, xln);
    k_mean<<<(BB * DD + 255) / 256, 256, 0, stream>>>(xln, pooled);
    k_mlp<<<BB, 256, 0, stream>>>(pooled, mlp_w1, mlp_b1, mlp_w2, mlp_b2, mlp_w3, mlp_b3,
                                  (float*)d_out);
}

// Round 2
// 2776.149 us; speedup vs baseline: 1.9763x; 1.9763x over previous
//
#include <hip/hip_runtime.h>
#include <math.h>

#define BB 8
#define NN 2048
#define PP 64
#define KK 32
#define DD 384
#define DEPTH 12
#define DI 768
#define DS 16
#define DCONV 4
#define DTR 24
#define NC 40
#define LL 128  // 2*PP
#define XROW (DTR + 2 * DS)  // 56

// ---------------------------------------------------------------- helpers
__device__ __forceinline__ float gelu_exact(float x) {
    return 0.5f * x * (1.0f + erff(x * 0.70710678118654752440f));
}
__device__ __forceinline__ float siluf(float x) {
    return x / (1.0f + expf(-x));
}
__device__ __forceinline__ unsigned spread_bits(unsigned v) {
    v &= 1023u;
    v = (v | (v << 16)) & 50331903u;
    v = (v | (v << 8)) & 50393103u;
    v = (v | (v << 4)) & 51130563u;
    v = (v | (v << 2)) & 153391689u;
    return v;
}

// ---------------------------------------------------------------- patch embed
// one workgroup per (b, p): KNN select (stable argmin x32 via packed shuffle-min),
// then 3->64->128->384 MLP over 32 neighbors, max-pool over neighbors.
__global__ __launch_bounds__(256) void k_patch_embed(
    const float* __restrict__ data,
    const float* __restrict__ w1, const float* __restrict__ b1,
    const float* __restrict__ g1, const float* __restrict__ be1,
    const float* __restrict__ w2, const float* __restrict__ b2,
    const float* __restrict__ g2, const float* __restrict__ be2,
    const float* __restrict__ w3, const float* __restrict__ b3,
    const float* __restrict__ g3, const float* __restrict__ be3,
    float* __restrict__ tokens, float* __restrict__ centers)
{
    const int bp = blockIdx.x;
    const int b = bp >> 6, p = bp & 63;
    const int tid = threadIdx.x;
    const int lane = tid & 63, wid = tid >> 6;
    const float* X = data + (size_t)b * NN * 3;
    const float inv_den = 0.99999500003749968752f; // 1/sqrt(1+1e-5)

    const float cx = X[p * 32 * 3 + 0];
    const float cy = X[p * 32 * 3 + 1];
    const float cz = X[p * 32 * 3 + 2];
    if (tid == 0) {
        centers[(b * PP + p) * 3 + 0] = cx;
        centers[(b * PP + p) * 3 + 1] = cy;
        centers[(b * PP + p) * 3 + 2] = cz;
    }

    __shared__ float d2[NN];
    for (int i = tid; i < NN; i += 256) {
        float dx = cx - X[i * 3 + 0];
        float dy = cy - X[i * 3 + 1];
        float dz = cz - X[i * 3 + 2];
        d2[i] = dx * dx + dy * dy + dz * dz;
    }
    __syncthreads();

    __shared__ int knn[KK];
    __shared__ unsigned long long wred[4];
    for (int k = 0; k < KK; k++) {
        unsigned long long best = ~0ull;
        for (int i = tid; i < NN; i += 256) {
            // d2 >= 0 -> float bits are order-preserving as unsigned
            unsigned long long pk =
                ((unsigned long long)__float_as_uint(d2[i]) << 32) | (unsigned)i;
            best = pk < best ? pk : best;
        }
#pragma unroll
        for (int off = 32; off; off >>= 1) {
            unsigned long long o = __shfl_xor(best, off);
            best = o < best ? o : best;
        }
        if (lane == 0) wred[wid] = best;
        __syncthreads();
        if (tid == 0) {
            unsigned long long m = wred[0];
#pragma unroll
            for (int w = 1; w < 4; w++) m = wred[w] < m ? wred[w] : m;
            int idx = (int)(m & 0xffffffffu);
            knn[k] = idx;
            d2[idx] = 3.4e38f;
        }
        __syncthreads();
    }

    __shared__ float nx[KK * 3];
    for (int j = tid; j < KK; j += 256) {
        int q = knn[j];
        nx[j * 3 + 0] = X[q * 3 + 0] - cx;
        nx[j * 3 + 1] = X[q * 3 + 1] - cy;
        nx[j * 3 + 2] = X[q * 3 + 2] - cz;
    }
    __syncthreads();

    __shared__ float h1[KK * 64];
    for (int e = tid; e < KK * 64; e += 256) {
        int j = e >> 6, c = e & 63;
        float v = nx[j * 3 + 0] * w1[c * 3 + 0] + nx[j * 3 + 1] * w1[c * 3 + 1] +
                  nx[j * 3 + 2] * w1[c * 3 + 2] + b1[c];
        v = v * (g1[c] * inv_den) + be1[c];
        h1[j * 64 + c] = gelu_exact(v);
    }
    __syncthreads();

    __shared__ float h2[KK * 128];
    for (int e = tid; e < KK * 128; e += 256) {
        int j = e >> 7, c = e & 127;
        const float4* wr = (const float4*)(w2 + (size_t)c * 64);
        const float4* hr = (const float4*)(h1 + j * 64);
        float acc = 0.f;
#pragma unroll
        for (int q = 0; q < 16; q++) {
            float4 wv = wr[q], hv = hr[q];
            acc += hv.x * wv.x + hv.y * wv.y + hv.z * wv.z + hv.w * wv.w;
        }
        float v = (acc + b2[c]) * (g2[c] * inv_den) + be2[c];
        h2[j * 128 + c] = gelu_exact(v);
    }
    __syncthreads();

    for (int c = tid; c < DD; c += 256) {
        const float4* wr = (const float4*)(w3 + (size_t)c * 128);
        float sc = g3[c] * inv_den;
        float bi2 = b3[c], sh = be3[c];
        float m = -3.4e38f;
        for (int j = 0; j < KK; j++) {
            const float4* hr = (const float4*)(h2 + j * 128);
            float acc = 0.f;
#pragma unroll
            for (int q = 0; q < 32; q++) {
                float4 wv = wr[q], hv = hr[q];
                acc += hv.x * wv.x + hv.y * wv.y + hv.z * wv.z + hv.w * wv.w;
            }
            float v = (acc + bi2) * sc + sh;
            m = fmaxf(m, v);
        }
        tokens[((size_t)b * PP + p) * DD + c] = m;
    }
}

// ---------------------------------------------------------------- SFC orders
__global__ __launch_bounds__(64) void k_sfc(const float* __restrict__ centers,
                                            int* __restrict__ order_h,
                                            int* __restrict__ order_th)
{
    const int b = blockIdx.x;
    const int tid = threadIdx.x; // 0..63
    float cc[3];
    cc[0] = centers[(b * PP + tid) * 3 + 0];
    cc[1] = centers[(b * PP + tid) * 3 + 1];
    cc[2] = centers[(b * PP + tid) * 3 + 2];

    __shared__ float csh[PP][3];
    __shared__ float slo[3], shi[3];
    csh[tid][0] = cc[0]; csh[tid][1] = cc[1]; csh[tid][2] = cc[2];
    __syncthreads();
    if (tid == 0) {
        for (int k = 0; k < 3; k++) {
            float lo = csh[0][k], hi = csh[0][k];
            for (int j = 1; j < PP; j++) { lo = fminf(lo, csh[j][k]); hi = fmaxf(hi, csh[j][k]); }
            slo[k] = lo; shi[k] = hi;
        }
    }
    __syncthreads();

    int q[3];
    for (int k = 0; k < 3; k++) {
        float t = (cc[k] - slo[k]) / (shi[k] - slo[k] + 1e-6f) * 1023.0f;
        int qi = (int)t;
        qi = qi < 0 ? 0 : (qi > 1023 ? 1023 : qi);
        q[k] = qi;
    }
    unsigned kh = spread_bits((unsigned)q[0]) | (spread_bits((unsigned)q[1]) << 1) |
                  (spread_bits((unsigned)q[2]) << 2);
    unsigned kt = spread_bits((unsigned)q[2]) | (spread_bits((unsigned)q[1]) << 1) |
                  (spread_bits((unsigned)q[0]) << 2);

    __shared__ unsigned khs[PP], kts[PP];
    khs[tid] = kh; kts[tid] = kt;
    __syncthreads();
    int rh = 0, rt = 0;
    for (int j = 0; j < PP; j++) {
        unsigned a = khs[j];
        rh += (a < kh) || (a == kh && j < tid);
        unsigned c = kts[j];
        rt += (c < kt) || (c == kt && j < tid);
    }
    order_h[b * PP + rh] = tid;
    order_th[b * PP + rt] = tid;
}

// ---------------------------------------------------------------- build token sequence
__global__ void k_build_t(const float* __restrict__ tokens,
                          const int* __restrict__ order_h, const int* __restrict__ order_th,
                          const float* __restrict__ hs, const float* __restrict__ hb,
                          const float* __restrict__ ts, const float* __restrict__ tb,
                          const float* __restrict__ pos, float* __restrict__ t)
{
    int idx = blockIdx.x * blockDim.x + threadIdx.x;
    if (idx >= BB * LL * DD) return;
    int d = idx % DD;
    int l = (idx / DD) % LL;
    int b = idx / (DD * LL);
    float v;
    if (l < PP) {
        int src = order_h[b * PP + l];
        v = tokens[((size_t)b * PP + src) * DD + d] * hs[d] + hb[d] + pos[l * DD + d];
    } else {
        int ll2 = l - PP;
        int src = order_th[b * PP + ll2];
        v = tokens[((size_t)b * PP + src) * DD + d] * ts[d] + tb[d] + pos[ll2 * DD + d];
    }
    t[idx] = v;
}

// ---------------------------------------------------------------- layernorm: one wave per row, no barriers
__global__ __launch_bounds__(64) void k_ln(const float* __restrict__ x,
                                           const float* __restrict__ g,
                                           const float* __restrict__ bb,
                                           float* __restrict__ y)
{
    const int row = blockIdx.x;
    const int tid = threadIdx.x;
    const float* xr = x + (size_t)row * DD;
    float v[6];
    float s = 0.f;
#pragma unroll
    for (int j = 0; j < 6; j++) { v[j] = xr[tid + 64 * j]; s += v[j]; }
#pragma unroll
    for (int off = 32; off; off >>= 1) s += __shfl_xor(s, off);
    float mean = s * (1.0f / DD);
    float vs = 0.f;
#pragma unroll
    for (int j = 0; j < 6; j++) { float dd = v[j] - mean; vs += dd * dd; }
#pragma unroll
    for (int off = 32; off; off >>= 1) vs += __shfl_xor(vs, off);
    float inv = 1.0f / sqrtf(vs * (1.0f / DD) + 1e-5f);
#pragma unroll
    for (int j = 0; j < 6; j++) {
        int i = tid + 64 * j;
        y[(size_t)row * DD + i] = (v[j] - mean) * inv * g[i] + bb[i];
    }
}

// ---------------------------------------------------------------- register-tiled fp32 GEMM
// C[n,m] = A[M,K] * B[N,K]^T.  64x64 tile, 256 threads, 4x4 micro-tile.
// MODE: 0 = store (with optional bias), 1 = atomicAdd (split-K / residual accum; bias must be null)
// ACT:  0 = none, 1 = softplus
template <int ACT, int MODE>
__global__ __launch_bounds__(256) void k_gemm64(
    const float* __restrict__ A, int lda,
    const float* __restrict__ B, int ldb,
    const float* __restrict__ bias,
    float* __restrict__ C, int ldc,
    int M, int N, int K, int kchunk)
{
    __shared__ float As[16][68];  // 68: rows 16B-aligned (272B), bank stride 4
    __shared__ float Bs[16][68];
    const int tid = threadIdx.x;
    const int tx = tid & 15, ty = tid >> 4;
    const int m0 = blockIdx.y * 64, n0 = blockIdx.x * 64;
    const int kbeg = blockIdx.z * kchunk;
    const int kend = (kbeg + kchunk < K) ? (kbeg + kchunk) : K;

    const int la = tid * 4;
    const int lm = la >> 4;   // 0..63 (tile row)
    const int lk = la & 15;   // 0,4,8,12

    float acc[4][4] = {};

    for (int k0 = kbeg; k0 < kend; k0 += 16) {
        // stage A (64x16) and B (64x16), transposed to K-major in LDS
        float4 av = make_float4(0.f, 0.f, 0.f, 0.f);
        float4 bv = make_float4(0.f, 0.f, 0.f, 0.f);
        int ak = k0 + lk;
        int arow = m0 + lm, brow = n0 + lm;
        if (arow < M) {
            if (ak + 3 < kend) av = *(const float4*)(A + (size_t)arow * lda + ak);
            else {
                float tmp[4] = {0.f, 0.f, 0.f, 0.f};
                for (int q = 0; q < 4; q++) if (ak + q < kend) tmp[q] = A[(size_t)arow * lda + ak + q];
                av = make_float4(tmp[0], tmp[1], tmp[2], tmp[3]);
            }
        }
        if (brow < N) {
            if (ak + 3 < kend) bv = *(const float4*)(B + (size_t)brow * ldb + ak);
            else {
                float tmp[4] = {0.f, 0.f, 0.f, 0.f};
                for (int q = 0; q < 4; q++) if (ak + q < kend) tmp[q] = B[(size_t)brow * ldb + ak + q];
                bv = make_float4(tmp[0], tmp[1], tmp[2], tmp[3]);
            }
        }
        As[lk + 0][lm] = av.x; As[lk + 1][lm] = av.y; As[lk + 2][lm] = av.z; As[lk + 3][lm] = av.w;
        Bs[lk + 0][lm] = bv.x; Bs[lk + 1][lm] = bv.y; Bs[lk + 2][lm] = bv.z; Bs[lk + 3][lm] = bv.w;
        __syncthreads();
#pragma unroll
        for (int kk = 0; kk < 16; kk++) {
            float4 a = *(const float4*)(&As[kk][ty * 4]);
            float4 b = *(const float4*)(&Bs[kk][tx * 4]);
            acc[0][0] += a.x * b.x; acc[0][1] += a.x * b.y; acc[0][2] += a.x * b.z; acc[0][3] += a.x * b.w;
            acc[1][0] += a.y * b.x; acc[1][1] += a.y * b.y; acc[1][2] += a.y * b.z; acc[1][3] += a.y * b.w;
            acc[2][0] += a.z * b.x; acc[2][1] += a.z * b.y; acc[2][2] += a.z * b.z; acc[2][3] += a.z * b.w;
            acc[3][0] += a.w * b.x; acc[3][1] += a.w * b.y; acc[3][2] += a.w * b.z; acc[3][3] += a.w * b.w;
        }
        __syncthreads();
    }

    const int crow = m0 + ty * 4;
    const int ccol = n0 + tx * 4;
#pragma unroll
    for (int i = 0; i < 4; i++) {
        int r = crow + i;
        if (r >= M) continue;
        float* cp = C + (size_t)r * ldc + ccol;
        if (MODE == 0) {
            float vr[4];
#pragma unroll
            for (int j = 0; j < 4; j++) {
                float v = acc[i][j];
                if (bias && ccol + j < N) v += bias[ccol + j];
                if (ACT == 1) v = fmaxf(v, 0.f) + log1pf(expf(-fabsf(v)));
                vr[j] = v;
            }
            if (ccol + 3 < N) *(float4*)cp = make_float4(vr[0], vr[1], vr[2], vr[3]);
            else { for (int j = 0; j < 4; j++) if (ccol + j < N) cp[j] = vr[j]; }
        } else {
#pragma unroll
            for (int j = 0; j < 4; j++) {
                if (ccol + j < N) atomicAdd(&cp[j], acc[i][j]);
            }
        }
    }
}

// ---------------------------------------------------------------- zero-fill
__global__ void k_zero(float* __restrict__ p, int n)
{
    int i = blockIdx.x * blockDim.x + threadIdx.x;
    if (i < n) p[i] = 0.f;
}

// ---------------------------------------------------------------- causal depthwise conv + silu
__global__ void k_conv(const float* __restrict__ xz, const float* __restrict__ cw,
                       const float* __restrict__ cb, float* __restrict__ xc)
{
    int idx = blockIdx.x * blockDim.x + threadIdx.x;
    if (idx >= BB * LL * DI) return;
    int c = idx % DI;
    int l = (idx / DI) % LL;
    int b = idx / (DI * LL);
    float acc = cb[c];
#pragma unroll
    for (int j = 0; j < DCONV; j++) {
        int lt = l - (DCONV - 1) + j;
        if (lt >= 0) acc += xz[((size_t)(b * LL + lt)) * (2 * DI) + c] * cw[c * DCONV + j];
    }
    xc[idx] = siluf(acc);
}

// ---------------------------------------------------------------- selective scan: 16 lanes per (b,d) channel
__global__ __launch_bounds__(256) void k_scan(
    const float* __restrict__ delta, const float* __restrict__ xdbl,
    const float* __restrict__ xc, const float* __restrict__ xz,
    const float* __restrict__ Alog, const float* __restrict__ Dp,
    float* __restrict__ y)
{
    const int tid = threadIdx.x;
    const int s = tid & 15;
    const int ch = blockIdx.x * 16 + (tid >> 4);  // 0..6143
    const int b = ch / DI, d = ch % DI;
    const float As_ = -__expf(Alog[d * DS + s]);
    const float Dd = Dp[d];
    float h = 0.f;
    for (int t = 0; t < LL; t++) {
        size_t row = (size_t)b * LL + t;
        float dt = delta[row * DI + d];
        float u  = xc[row * DI + d];
        float Bv = xdbl[row * XROW + DTR + s];
        float Cv = xdbl[row * XROW + DTR + DS + s];
        h = h * __expf(dt * As_) + dt * u * Bv;
        float p = h * Cv;
        p += __shfl_xor(p, 1, 16);
        p += __shfl_xor(p, 2, 16);
        p += __shfl_xor(p, 4, 16);
        p += __shfl_xor(p, 8, 16);
        if (s == 0) {
            float z = xz[row * (2 * DI) + DI + d];
            y[row * DI + d] = (p + Dd * u) * siluf(z);
        }
    }
}

// ---------------------------------------------------------------- mean over L
__global__ void k_mean(const float* __restrict__ xln, float* __restrict__ pooled)
{
    int idx = blockIdx.x * blockDim.x + threadIdx.x;
    if (idx >= BB * DD) return;
    int b = idx / DD, d = idx % DD;
    float sv = 0.f;
    for (int l = 0; l < LL; l++) sv += xln[((size_t)b * LL + l) * DD + d];
    pooled[idx] = sv / (float)LL;
}

// ---------------------------------------------------------------- head MLP (one block per batch)
__global__ __launch_bounds__(256) void k_mlp(const float* __restrict__ pooled,
    const float* __restrict__ w1, const float* __restrict__ b1,
    const float* __restrict__ w2, const float* __restrict__ b2,
    const float* __restrict__ w3, const float* __restrict__ b3,
    float* __restrict__ out)
{
    int b = blockIdx.x, tid = threadIdx.x;
    __shared__ float pl[DD];
    __shared__ float h1[256];
    __shared__ float h2[64];
    for (int i = tid; i < DD; i += 256) pl[i] = pooled[b * DD + i];
    __syncthreads();
    {
        float acc = b1[tid];
        const float* wr = w1 + (size_t)tid * DD;
        for (int k = 0; k < DD; k++) acc += pl[k] * wr[k];
        h1[tid] = fmaxf(acc, 0.f);
    }
    __syncthreads();
    if (tid < 64) {
        float acc = b2[tid];
        const float* wr = w2 + (size_t)tid * 256;
        for (int k = 0; k < 256; k++) acc += h1[k] * wr[k];
        h2[tid] = fmaxf(acc, 0.f);
    }
    __syncthreads();
    if (tid < NC) {
        float acc = b3[tid];
        const float* wr = w3 + (size_t)tid * 64;
        for (int k = 0; k < 64; k++) acc += h2[k] * wr[k];
        out[b * NC + tid] = acc;
    }
}

// ---------------------------------------------------------------- launch
extern "C" void kernel_launch(void* const* d_in, const int* in_sizes, int n_in,
                              void* d_out, int out_size, void* d_ws, size_t ws_size,
                              hipStream_t stream)
{
    const float* data      = (const float*)d_in[0];
    const float* pe_w1     = (const float*)d_in[1];
    const float* pe_b1     = (const float*)d_in[2];
    const float* pe_g1     = (const float*)d_in[3];
    const float* pe_be1    = (const float*)d_in[4];
    const float* pe_w2     = (const float*)d_in[5];
    const float* pe_b2     = (const float*)d_in[6];
    const float* pe_g2     = (const float*)d_in[7];
    const float* pe_be2    = (const float*)d_in[8];
    const float* pe_w3     = (const float*)d_in[9];
    const float* pe_b3     = (const float*)d_in[10];
    const float* pe_g3     = (const float*)d_in[11];
    const float* pe_be3    = (const float*)d_in[12];
    const float* oi_h_scale  = (const float*)d_in[13];
    const float* oi_h_shift  = (const float*)d_in[14];
    const float* oi_th_scale = (const float*)d_in[15];
    const float* oi_th_shift = (const float*)d_in[16];
    const float* pos_embed = (const float*)d_in[17];
    const float* blk_ln_g  = (const float*)d_in[18];
    const float* blk_ln_b  = (const float*)d_in[19];
    const float* blk_in_w  = (const float*)d_in[20];
    const float* blk_conv_w = (const float*)d_in[21];
    const float* blk_conv_b = (const float*)d_in[22];
    const float* blk_xp_w  = (const float*)d_in[23];
    const float* blk_dt_w  = (const float*)d_in[24];
    const float* blk_dt_b  = (const float*)d_in[25];
    const float* blk_Alog  = (const float*)d_in[26];
    const float* blk_D     = (const float*)d_in[27];
    const float* blk_out_w = (const float*)d_in[28];
    const float* norm_g    = (const float*)d_in[29];
    const float* norm_b    = (const float*)d_in[30];
    const float* mlp_w1    = (const float*)d_in[31];
    const float* mlp_b1    = (const float*)d_in[32];
    const float* mlp_w2    = (const float*)d_in[33];
    const float* mlp_b2    = (const float*)d_in[34];
    const float* mlp_w3    = (const float*)d_in[35];
    const float* mlp_b3    = (const float*)d_in[36];

    float* ws = (float*)d_ws;
    size_t off = 0;
    auto alloc = [&](size_t n) { float* p = ws + off; off += (n + 63) & ~(size_t)63; return p; };
    float* tokens  = alloc((size_t)BB * PP * DD);
    float* centers = alloc((size_t)BB * PP * 3);
    int*   order_h = (int*)alloc((size_t)BB * PP);
    int*   order_th= (int*)alloc((size_t)BB * PP);
    float* t    = alloc((size_t)BB * LL * DD);
    float* xln  = alloc((size_t)BB * LL * DD);
    float* xz   = alloc((size_t)BB * LL * 2 * DI);
    float* xc   = alloc((size_t)BB * LL * DI);
    float* xdbl = alloc((size_t)BB * LL * XROW);
    float* delta= alloc((size_t)BB * LL * DI);
    float* yb   = alloc((size_t)BB * LL * DI);
    float* pooled = alloc((size_t)BB * DD);

    k_patch_embed<<<BB * PP, 256, 0, stream>>>(data,
        pe_w1, pe_b1, pe_g1, pe_be1, pe_w2, pe_b2, pe_g2, pe_be2,
        pe_w3, pe_b3, pe_g3, pe_be3, tokens, centers);
    k_sfc<<<BB, 64, 0, stream>>>(centers, order_h, order_th);
    {
        int nt = BB * LL * DD;
        k_build_t<<<(nt + 255) / 256, 256, 0, stream>>>(tokens, order_h, order_th,
            oi_h_scale, oi_h_shift, oi_th_scale, oi_th_shift, pos_embed, t);
    }

    const int NR = BB * LL; // 1024
    for (int i = 0; i < DEPTH; i++) {
        const float* ln_g = blk_ln_g + i * DD;
        const float* ln_b = blk_ln_b + i * DD;
        const float* in_w = blk_in_w + (size_t)i * 2 * DI * DD;
        const float* cw   = blk_conv_w + (size_t)i * DI * DCONV;
        const float* cb   = blk_conv_b + (size_t)i * DI;
        const float* xp   = blk_xp_w + (size_t)i * XROW * DI;
        const float* dtw  = blk_dt_w + (size_t)i * DI * DTR;
        const float* dtb  = blk_dt_b + (size_t)i * DI;
        const float* Al   = blk_Alog + (size_t)i * DI * DS;
        const float* Dpp  = blk_D + (size_t)i * DI;
        const float* ow   = blk_out_w + (size_t)i * DD * DI;

        k_ln<<<NR, 64, 0, stream>>>(t, ln_g, ln_b, xln);
        // xz = xln @ in_w^T  (1024 x 1536, K=384)
        k_gemm64<0, 0><<<dim3(2 * DI / 64, NR / 64, 1), 256, 0, stream>>>(
            xln, DD, in_w, DD, nullptr, xz, 2 * DI, NR, 2 * DI, DD, DD);
        k_conv<<<(NR * DI + 255) / 256, 256, 0, stream>>>(xz, cw, cb, xc);
        // xdbl = xc @ xp^T  (1024 x 56, K=768) — split-K x4 with atomics
        k_zero<<<(NR * XROW + 255) / 256, 256, 0, stream>>>(xdbl, NR * XROW);
        k_gemm64<0, 1><<<dim3(1, NR / 64, 4), 256, 0, stream>>>(
            xc, DI, xp, DI, nullptr, xdbl, XROW, NR, XROW, DI, DI / 4);
        // delta = softplus(xdbl[:, :24] @ dt_w^T + dt_b)  (1024 x 768, K=24)
        k_gemm64<1, 0><<<dim3(DI / 64, NR / 64, 1), 256, 0, stream>>>(
            xdbl, XROW, dtw, DTR, dtb, delta, DI, NR, DI, DTR, DTR);
        k_scan<<<(BB * DI) / 16, 256, 0, stream>>>(delta, xdbl, xc, xz, Al, Dpp, yb);
        // t += yb @ out_w^T  (1024 x 384, K=768) — split-K x2 with atomics (residual accum)
        k_gemm64<0, 1><<<dim3(DD / 64, NR / 64, 2), 256, 0, stream>>>(
            yb, DI, ow, DI, nullptr, t, DD, NR, DD, DI, DI / 2);
    }

    k_ln<<<NR, 64, 0, stream>>>(t, norm_g, norm_b, xln);
    k_mean<<<(BB * DD + 255) / 256, 256, 0, stream>>>(xln, pooled);
    k_mlp<<<BB, 256, 0, stream>>>(pooled, mlp_w1, mlp_b1, mlp_w2, mlp_b2, mlp_w3, mlp_b3,
                                  (float*)d_out);
}